// Round 12
// baseline (82.024 us; speedup 1.0000x reference)
//
#include <hip/hip_runtime.h>

// ToeplitzMemoryProjection (HiPPO LagT, alpha=0.5 bilinear).
//
// Recurrence (exact in the truncated lower-tri Toeplitz algebra, verified
// rounds 1-11): with c = 1+0.25dt, g = (1-0.25dt)/c, beta = dt*u/c,
//   x_l[i] = g_l*(x_l[i-1] + x_{l-1}[i]) - x_{l-1}[i-1] + beta_l*[i==0]
//
// R12: BARRIER-FREE producer/consumer. Rounds 3-11 all serialized
// compute + store-drain through the per-chunk s_barrier (sum, not max).
//  - Compute = ONE wave/channel: lane j owns cols 4j..4j+3; tick T computes
//    row l = T-j. In-register 4-col chain; cross-lane via TWO dpp wave_shr:1
//    (neighbor col-3 values of ticks T-1 and T-2 = rows l, l-1 at col 4j-1).
//    g: per-tick b32 read; beta: broadcast b32 (lane0-selected). NO BARRIERS.
//  - Ring [128 rows][264-dword stride] (stride 264 => b128 writes/reads are
//    bank-uniform 8 dwords/bank). Write slot = row & 127.
//  - 4 store waves (64 cols each) flush 32-row chunks: poll done >= F+95
//    (row F+31 written by lane63 at tick F+94), 8x ds_read_b128,
//    lgkmcnt(0), publish progress = F+32 (slots reusable: LDS reads done,
//    HBM stores NOT waited), then 8 nontemporal dwordx4 stores.
//  - Compute back-pressure: before tick chunk T0 (writes rows [T0-63,T0+31],
//    overwriting slots of rows [T0-191,T0-97]) poll min(progress) >= T0-96.
//    Store stalls (queue-full) are absorbed in store waves only; compute
//    streams ahead => total time ~ max(store-drain, compute), not sum.
//  - Flag protocol: publishers s_waitcnt lgkmcnt(0) BEFORE flag ds_write
//    (prior LDS ops complete first); pollers read flag with lgkmcnt(0) +
//    memory clobber (later LDS ops can't hoist above). Monotonic counters,
//    overlapping slack windows => no deadlock. One __syncthreads after init.

namespace {

constexpr int LLEN  = 1024;
constexpr int NCHAN = 256;
constexpr int KCH   = 32;                  // rows/ticks per chunk
constexpr int NCHC  = 34;                  // compute chunks: T0 = 0..1056
constexpr int RROWS = 128;                 // ring rows (pow2)
constexpr int RSTR  = 264;                 // ring row stride, dwords
constexpr int GPAD  = 1152;                // g/b padded length

constexpr int G_OFF = 0;
constexpr int B_OFF = GPAD;
constexpr int F_OFF = 2 * GPAD;            // flags: done @+0, progress[4] @+4
constexpr int R_OFF = F_OFF + 8;           // ring (16B-aligned: 2312*4)
constexpr int LDS_FLOATS = R_OFF + RROWS * RSTR;
constexpr size_t LDS_BYTES = (size_t)LDS_FLOATS * 4;   // 144,416 B

using f32x4 = __attribute__((ext_vector_type(4))) float;
using i32x4 = __attribute__((ext_vector_type(4))) int;

__device__ __forceinline__ float dpp_shr1(float v) {
    // lane i <- lane i-1; lane 0 <- 0
    return __int_as_float(__builtin_amdgcn_update_dpp(
        0, __float_as_int(v), 0x138 /*WAVE_SHR1*/, 0xF, 0xF, false));
}
__device__ __forceinline__ unsigned lds_addr(const void* p) {
    return (unsigned)(unsigned long long)p;
}
__device__ __forceinline__ int poll_i32(const int* p) {
    int v;
    asm volatile("ds_read_b32 %0, %1\n\ts_waitcnt lgkmcnt(0)"
                 : "=v"(v) : "v"(lds_addr(p)) : "memory");
    return v;
}
__device__ __forceinline__ i32x4 poll_i32x4(const int* p) {
    i32x4 v;
    asm volatile("ds_read_b128 %0, %1\n\ts_waitcnt lgkmcnt(0)"
                 : "=v"(v) : "v"(lds_addr(p)) : "memory");
    return v;
}
__device__ __forceinline__ void publish_i32(int* p, int val) {
    // prior LDS ops complete, THEN flag becomes visible
    asm volatile("s_waitcnt lgkmcnt(0)\n\tds_write_b32 %0, %1"
                 :: "v"(lds_addr(p)), "v"(val) : "memory");
}

// One 32-tick compute chunk. MASKED: ramp (T0<64) / drain (T0>992) edges.
template <bool MASKED>
__device__ __forceinline__ void ticks32(
    const int T0, const int lane, const bool lane0,
    const float* __restrict__ g_arr, const float* __restrict__ b_arr,
    float* __restrict__ ring,
    float& p0, float& p1, float& p2, float& p3, float& p3p)
{
    const int l0 = T0 - lane;              // this lane's row at s=0
    int slot = l0 & (RROWS - 1);
    const int colo = lane * 4;
    #pragma unroll
    for (int s = 0; s < KCH; ++s) {
        const int l = l0 + s;
        const int li = MASKED ? max(l, 0) : l;   // pad covers the high side
        const float g  = g_arr[li];
        const float bv = b_arr[T0 + s];          // broadcast (<= 1087 < GPAD)
        const float ulc = dpp_shr1(p3);          // x_l[4j-1]     (nbr, T-1)
        const float ulp = dpp_shr1(p3p);         // x_{l-1}[4j-1] (nbr, T-2)
        const float bsel = lane0 ? bv : 0.0f;
        const float n0 = fmaf(g, ulc + p0, bsel - ulp);
        const float n1 = fmaf(g, n0 + p1, -p0);
        const float n2 = fmaf(g, n1 + p2, -p1);
        const float n3 = fmaf(g, n2 + p3, -p2);
        f32x4 v; v[0] = n0; v[1] = n1; v[2] = n2; v[3] = n3;
        // OOB-row garbage writes are slot-safe (see back-pressure proof)
        *reinterpret_cast<f32x4*>(&ring[slot * RSTR + colo]) = v;
        slot = (slot + 1) & (RROWS - 1);
        if (MASKED) {
            const bool act = (unsigned)l < (unsigned)LLEN;
            p3p = act ? p3 : p3p;
            p0 = act ? n0 : p0;  p1 = act ? n1 : p1;
            p2 = act ? n2 : p2;  p3 = act ? n3 : p3;
        } else {
            p3p = p3;
            p0 = n0; p1 = n1; p2 = n2; p3 = n3;
        }
    }
}

__global__ __launch_bounds__(320, 1)
void toeplitz_scan(const float* __restrict__ vin,   // inputs (L, 256)
                   const float* __restrict__ dtin,  // dt     (L, 256)
                   float* __restrict__ out)         // (L, 256, 256)
{
    extern __shared__ float lds[];
    float* g_arr = lds + G_OFF;   // [GPAD]
    float* b_arr = lds + B_OFF;   // [GPAD]
    int*   flags = (int*)lds + F_OFF;  // done, progress[4]
    float* ring  = lds + R_OFF;   // [RROWS][RSTR]

    const int ch  = blockIdx.x;
    const int tid = threadIdx.x;

    // ---- per-channel g[l], beta[l] (+ pad), 320 threads ----
    #pragma unroll
    for (int k = 0; k < 4; ++k) {
        const int l = tid + 320 * k;           // covers 0..1279
        if (l < LLEN) {
            const float d = dtin[l * NCHAN + ch];
            const float u = vin[l * NCHAN + ch];
            const float ic = 1.0f / (1.0f + 0.25f * d);
            g_arr[l] = (1.0f - 0.25f * d) * ic;
            b_arr[l] = d * u * ic;
        } else if (l < GPAD) {
            g_arr[l] = 1.0f;
            b_arr[l] = 0.0f;
        }
    }
    if (tid < 8) flags[tid] = 0;
    __syncthreads();                            // the ONLY barrier

    const int wv = tid >> 6, lane = tid & 63;

    if (wv == 0) {
        // ========================= compute wave =========================
        const bool lane0 = (lane == 0);
        float p0 = 0.f, p1 = 0.f, p2 = 0.f, p3 = 0.f, p3p = 0.f;

        for (int c = 0; c < NCHC; ++c) {
            const int T0 = c * KCH;
            // back-pressure: slots of rows [T0-191, T0-97] must be consumed
            const int need = T0 - 96;
            if (need > 0) {
                for (;;) {
                    const i32x4 pv = poll_i32x4(flags + 4);
                    const int m = min(min(pv[0], pv[1]), min(pv[2], pv[3]));
                    if (m >= need) break;
                    __builtin_amdgcn_s_sleep(2);
                }
            }
            const bool fast = (T0 >= 64) && (T0 <= 992);
            if (fast)
                ticks32<false>(T0, lane, lane0, g_arr, b_arr, ring,
                               p0, p1, p2, p3, p3p);
            else
                ticks32<true>(T0, lane, lane0, g_arr, b_arr, ring,
                              p0, p1, p2, p3, p3p);
            if (lane0) publish_i32(flags + 0, T0 + KCH);   // done rows/ticks
        }
    } else {
        // ========================= store waves ==========================
        const int sw = wv - 1;                  // 0..3, owns 64 columns
        const int rq = lane >> 4;               // row within 4-row group
        const int colbase = sw * 64 + (lane & 15) * 4;
        float* const outb = out + (size_t)(ch * 256 + colbase);

        for (int F = 0; F <= LLEN - KCH; F += KCH) {
            // row F+31 written by lane 63 at tick F+94 -> need done >= F+95
            while (poll_i32(flags + 0) < F + 95)
                __builtin_amdgcn_s_sleep(2);
            f32x4 v[8];
            #pragma unroll
            for (int q = 0; q < 8; ++q) {
                const int row = F + rq + 4 * q;
                v[q] = *reinterpret_cast<const f32x4*>(
                    &ring[(row & (RROWS - 1)) * RSTR + colbase]);
            }
            // LDS reads done -> slots reusable (do NOT wait on HBM stores)
            asm volatile("s_waitcnt lgkmcnt(0)" ::: "memory");
            if (lane == 0) publish_i32(flags + 4 + sw, F + KCH);
            #pragma unroll
            for (int q = 0; q < 8; ++q) {
                __builtin_nontemporal_store(
                    v[q], reinterpret_cast<f32x4*>(
                              outb + (size_t)(F + rq + 4 * q) * (NCHAN * 256)));
            }
        }
    }
}

} // namespace

extern "C" void kernel_launch(void* const* d_in, const int* in_sizes, int n_in,
                              void* d_out, int out_size, void* d_ws, size_t ws_size,
                              hipStream_t stream) {
    (void)in_sizes; (void)n_in; (void)d_ws; (void)ws_size; (void)out_size;
    const float* vin  = (const float*)d_in[0];   // "inputs"
    const float* dtin = (const float*)d_in[1];   // "dt"
    float* out = (float*)d_out;

    (void)hipFuncSetAttribute(reinterpret_cast<const void*>(toeplitz_scan),
                              hipFuncAttributeMaxDynamicSharedMemorySize,
                              (int)LDS_BYTES);

    toeplitz_scan<<<NCHAN, 320, LDS_BYTES, stream>>>(vin, dtin, out);
}

// Round 13
// 75.250 us; speedup vs baseline: 1.0900x; 1.0900x over previous
//
#include <hip/hip_runtime.h>

// ToeplitzMemoryProjection (HiPPO LagT, alpha=0.5 bilinear).
//
// Recurrence (exact in the truncated lower-tri Toeplitz algebra, verified
// rounds 1-12): with c = 1+0.25dt, g = (1-0.25dt)/c, beta = dt*u/c,
//   x_l[i] = g_l*(x_l[i-1] + x_{l-1}[i]) - x_{l-1}[i-1] + beta_l*[i==0]
//
// R13 = R9 (best, 65.6us: column-per-lane wavefront, KCH=32, SKEW=96,
// row-indexed ring RSLOT=128, flush-at-end, LDS-only barriers) with the
// DS-instruction count cut ~40% (the fitted bottleneck across rounds 1-12
// is LDS-pipe instruction throughput, ~5.8cy/b32, ~12cy/b128):
//  - g reads: 32 per-lane b32 -> 8 broadcast ds_read_b128 of g[bl..bl+31]
//    (aligned, conflict-free) + per-tick DPP chain: lane j's g at tick s
//    equals lane j-1's at s-1; lane0 injects the broadcast value. The g
//    chain is independent of the x chain (hides under it). Seeded once at
//    bl==64 (one b32); masked edge chunks keep per-lane clamped reads.
//  - hb reads: 32 broadcast b32 -> ONE b32 (lane s&31 reads row bl+s col63;
//    32-way bank alias ~64cy, cheaper than 32 instrs) + 32 v_readlane
//    redistributions on the idle VALU/SALU pipes. W0 reads b_arr[T0+lane&31]
//    (conflict-free).
//  - ring writes (32 b32) + flush (8 b128 + 8 nontemporal dwordx4) + barrier
//    structure byte-identical to R9 (all residue/staleness proofs unchanged).

namespace {

constexpr int LLEN   = 1024;
constexpr int NCHAN  = 256;
constexpr int KCH    = 32;                 // ticks per chunk
constexpr int SKEW   = 96;                 // wave skew; 96-63=33 > KCH-1
constexpr int RSLOT  = 128;                // row slots per ring (pow2)
constexpr int NCHUNK = 43;                 // covers ticks [0,1376) >= 1375
constexpr int GPAD   = 1152;               // g/b padded length

constexpr int G_OFF = 0;
constexpr int B_OFF = GPAD;
constexpr int R_OFF = 2 * GPAD;
constexpr int LDS_FLOATS = R_OFF + 4 * RSLOT * 64;
constexpr size_t LDS_BYTES = (size_t)LDS_FLOATS * 4;   // 140288 B

using f32x4 = __attribute__((ext_vector_type(4))) float;

__device__ __forceinline__ float dpp_shr1(float v) {
    // lane i <- lane i-1; lane 0 <- 0
    return __int_as_float(__builtin_amdgcn_update_dpp(
        0, __float_as_int(v), 0x138 /*WAVE_SHR1*/, 0xF, 0xF, false));
}
__device__ __forceinline__ float rdlane(float v, int s) {
    return __int_as_float(__builtin_amdgcn_readlane(__float_as_int(v), s));
}
__device__ __forceinline__ void compiler_mem_fence() {
    asm volatile("" ::: "memory");
}
// LDS-only barrier: orders ring handoffs without draining the store queue.
__device__ __forceinline__ void lds_barrier() {
    __builtin_amdgcn_sched_barrier(0);
    asm volatile("s_waitcnt lgkmcnt(0)" ::: "memory");
    __builtin_amdgcn_s_barrier();
    __builtin_amdgcn_sched_barrier(0);
}

// One 32-tick chunk.
// FAST path: g via broadcast b128 + DPP chain; hb via 1 b32 + readlane.
// MASKED path (edges, ~5 chunks/wave): R9's per-tick clamped reads.
template <bool W0, bool MASKED>
__device__ __forceinline__ void do_chunk(
    const int T0, const int bl, const int lane, const bool lane0,
    const float* __restrict__ g_arr, const float* __restrict__ b_arr,
    const float* __restrict__ lf_ring, float* __restrict__ my_ring,
    float& g_cur, float& prev_own, float& prev_left)
{
    if (!MASKED) {
        // ---- gathers: 8 broadcast b128 (g) + 1 b32 (hb) ----
        f32x4 gb[8];
        const f32x4* gsrc = reinterpret_cast<const f32x4*>(g_arr + bl);
        #pragma unroll
        for (int q = 0; q < 8; ++q) gb[q] = gsrc[q];   // g[bl..bl+31], bcast
        float hvv;
        if (W0) hvv = b_arr[T0 + (lane & 31)];          // conflict-free
        else    hvv = lf_ring[(((bl + (lane & 31)) & (RSLOT - 1)) << 6) + 63];
        float hbs[KCH];
        #pragma unroll
        for (int s = 0; s < KCH; ++s) hbs[s] = rdlane(hvv, s);  // uniform

        const int m0 = bl - lane;
        #pragma unroll
        for (int s = 0; s < KCH; ++s) {
            const float gj = dpp_shr1(g_cur);
            g_cur = lane0 ? gb[s >> 2][s & 3] : gj;     // g[m0+s] per lane
            const float u = dpp_shr1(prev_own);
            float cl, ct;
            if (W0) { cl = u;
                      ct = (lane0 ? hbs[s] : 0.0f) - prev_left; }
            else    { cl = u + (lane0 ? hbs[s] : 0.0f);
                      ct = 0.0f - prev_left; }
            const float x = fmaf(g_cur, cl, fmaf(g_cur, prev_own, ct));
            my_ring[(((m0 + s) & (RSLOT - 1)) << 6) + lane] = x;
            prev_left = cl;
            prev_own  = x;
        }
    } else {
        // ---- masked edges: R9 body (g chain not maintained here) ----
        const int m0 = bl - lane;
        #pragma unroll
        for (int s = 0; s < KCH; ++s) {
            const int li = min(max(m0 + s, 0), LLEN - 1);
            const float gg = g_arr[li];
            float hb;
            if (W0) hb = b_arr[T0 + s];                 // pad covers range
            else    hb = lf_ring[(((bl + s) & (RSLOT - 1)) << 6) + 63];
            float cl = dpp_shr1(prev_own);
            float ct;
            if (W0) { ct = (lane0 ? hb : 0.0f) - prev_left; }
            else    { cl += lane0 ? hb : 0.0f;
                      ct = 0.0f - prev_left; }
            const float x = fmaf(gg, cl, fmaf(gg, prev_own, ct));
            my_ring[(((m0 + s) & (RSLOT - 1)) << 6) + lane] = x;
            const bool act = (unsigned)(m0 + s) < (unsigned)LLEN;
            prev_left = act ? cl : prev_left;
            prev_own  = act ? x  : prev_own;
        }
    }
}

__global__ __launch_bounds__(256, 1)
void toeplitz_scan(const float* __restrict__ vin,   // inputs (L, 256)
                   const float* __restrict__ dtin,  // dt     (L, 256)
                   float* __restrict__ out)         // (L, 256, 256)
{
    extern __shared__ float lds[];
    float* g_arr = lds + G_OFF;   // [GPAD]
    float* b_arr = lds + B_OFF;   // [GPAD]
    float* ring  = lds + R_OFF;   // [4][RSLOT][64], row-indexed slots

    const int ch  = blockIdx.x;
    const int tid = threadIdx.x;

    // ---- per-channel g[l], beta[l] (+ pad) ----
    #pragma unroll
    for (int k = 0; k < LLEN / 256; ++k) {
        const int l = tid + 256 * k;
        const float d = dtin[l * NCHAN + ch];
        const float u = vin[l * NCHAN + ch];
        const float ic = 1.0f / (1.0f + 0.25f * d);
        g_arr[l] = (1.0f - 0.25f * d) * ic;
        b_arr[l] = d * u * ic;
    }
    if (tid < GPAD - LLEN) {
        g_arr[LLEN + tid] = 1.0f;
        b_arr[LLEN + tid] = 0.0f;
    }
    __syncthreads();

    const int wave = tid >> 6, lane = tid & 63;
    const bool w0    = (wave == 0);
    const bool lane0 = (lane == 0);
    const int wskew  = wave * SKEW;

    float* my_ring = ring + wave * (RSLOT * 64);
    const float* lf_ring = ring + (wave > 0 ? (wave - 1) : 0) * (RSLOT * 64);

    float g_cur = 0.0f, prev_own = 0.0f, prev_left = 0.0f;

    const int rq = lane >> 4;              // flush: row within 4-row group
    const int cq = (lane & 15) << 2;       // flush: col-quad start
    float* const out_col = out + (size_t)(ch * 256 + wave * 64 + cq);

    for (int c = 0; c < NCHUNK; ++c) {
        const int T0 = c * KCH;
        const int bl = T0 - wskew;         // lane0's row at s=0 (mult of 32)

        if (bl >= 0 && bl <= 1056) {       // any lane active this chunk
            const bool fast = (bl >= 64) && (bl <= LLEN - KCH);
            if (bl == 64) g_cur = g_arr[63 - lane];   // seed the g chain
            if (w0) {
                if (fast)
                    do_chunk<true, false>(T0, bl, lane, lane0, g_arr, b_arr,
                                          lf_ring, my_ring, g_cur,
                                          prev_own, prev_left);
                else
                    do_chunk<true, true>(T0, bl, lane, lane0, g_arr, b_arr,
                                         lf_ring, my_ring, g_cur,
                                         prev_own, prev_left);
            } else {
                if (fast)
                    do_chunk<false, false>(T0, bl, lane, lane0, g_arr, b_arr,
                                           lf_ring, my_ring, g_cur,
                                           prev_own, prev_left);
                else
                    do_chunk<false, true>(T0, bl, lane, lane0, g_arr, b_arr,
                                          lf_ring, my_ring, g_cur,
                                          prev_own, prev_left);
            }
        }

        // ---- flush rows [F, F+31] (complete at tick T0+30, same wave) ----
        const int F = T0 - wskew - 64;
        if (F >= 0 && F <= LLEN - KCH) {
            compiler_mem_fence();          // ring writes stay above reads
            const float* rb = my_ring + ((F & (RSLOT - 1)) << 6) + cq;
            float* ob = out_col + (size_t)(F + rq) * (NCHAN * 256);
            #pragma unroll
            for (int q = 0; q < 8; ++q) {
                const f32x4 v =
                    *reinterpret_cast<const f32x4*>(rb + ((4 * q + rq) << 6));
                __builtin_nontemporal_store(v, reinterpret_cast<f32x4*>(ob));
                ob += (size_t)4 * (NCHAN * 256);
            }
        }
        lds_barrier();
    }
}

} // namespace

extern "C" void kernel_launch(void* const* d_in, const int* in_sizes, int n_in,
                              void* d_out, int out_size, void* d_ws, size_t ws_size,
                              hipStream_t stream) {
    (void)in_sizes; (void)n_in; (void)d_ws; (void)ws_size; (void)out_size;
    const float* vin  = (const float*)d_in[0];   // "inputs"
    const float* dtin = (const float*)d_in[1];   // "dt"
    float* out = (float*)d_out;

    (void)hipFuncSetAttribute(reinterpret_cast<const void*>(toeplitz_scan),
                              hipFuncAttributeMaxDynamicSharedMemorySize,
                              (int)LDS_BYTES);

    toeplitz_scan<<<NCHAN, 256, LDS_BYTES, stream>>>(vin, dtin, out);
}

// Round 14
// 68.083 us; speedup vs baseline: 1.2048x; 1.1053x over previous
//
#include <hip/hip_runtime.h>

// ToeplitzMemoryProjection (HiPPO LagT, alpha=0.5 bilinear).
//
// Recurrence (exact in the truncated lower-tri Toeplitz algebra, verified
// rounds 1-13): with c = 1+0.25dt, g = (1-0.25dt)/c, beta = dt*u/c,
//   x_l[i] = g_l*(x_l[i-1] + x_{l-1}[i]) - x_{l-1}[i-1] + beta_l*[i==0]
//
// R14 = R9 (best, 65.6us) + two changes that cut DS issue count and move
// store-queue stalls off the barrier path -- with NO new serial work
// (R13's lesson: chains don't hide at 1 wave/SIMD):
//  - ds_read2_b32 gathers: g[bl-lane+2q, +2q+1] as 16 paired reads
//    (offsets 2q/2q+1); hb col-63 of slot pairs as 16 paired reads
//    (per 4-slot base: offsets 63/127, then 191/255). 104 -> 72 DS
//    instr/wave/phase, identical data, identical bank behavior.
//  - LAG-96 EARLY FLUSH: at phase start, read rows [bl-96, bl-65]
//    (complete 1-2 chunks ago, same wave), wait, store IMMEDIATELY
//    (R10 erred by holding 32 VGPRs through the ticks), sched_barrier,
//    then gathers+ticks. Store back-pressure overlaps the tick chain
//    instead of serializing at the barrier.
//    Residues mod 128: flush reads bl+{32..63}, phase writes bl+{-63..31}
//    -> disjoint (R10 proof). Rows bl-96..bl-65 all written by end of
//    chunk c-1 (lane63 row bl-65 at tick T0-2), same-wave program order.
//  - Ring writes (32 b32), tick bodies, masked edges, LDS-only barrier:
//    byte-identical to R9.

namespace {

constexpr int LLEN   = 1024;
constexpr int NCHAN  = 256;
constexpr int KCH    = 32;                 // ticks per chunk
constexpr int SKEW   = 96;                 // wave skew; 96-63=33 > KCH-1
constexpr int RSLOT  = 128;                // row slots per ring (pow2)
constexpr int NCHUNK = 44;                 // w3 last flush F=992 @ T0=1376
constexpr int GPAD   = 1152;               // g/b padded length

constexpr int G_OFF = 0;
constexpr int B_OFF = GPAD;
constexpr int R_OFF = 2 * GPAD;
constexpr int LDS_FLOATS = R_OFF + 4 * RSLOT * 64;
constexpr size_t LDS_BYTES = (size_t)LDS_FLOATS * 4;   // 140288 B

using f32x4 = __attribute__((ext_vector_type(4))) float;
using f32x2 = __attribute__((ext_vector_type(2))) float;

__device__ __forceinline__ float dpp_shr1(float v) {
    // lane i <- lane i-1; lane 0 <- 0
    return __int_as_float(__builtin_amdgcn_update_dpp(
        0, __float_as_int(v), 0x138 /*WAVE_SHR1*/, 0xF, 0xF, false));
}
__device__ __forceinline__ unsigned lds_a(const void* p) {
    return (unsigned)(unsigned long long)p;
}
__device__ __forceinline__ void ds_rd128(f32x4& d, unsigned a, int imm) {
    asm volatile("ds_read_b128 %0, %1 offset:%2" : "=v"(d) : "v"(a), "i"(imm));
}
__device__ __forceinline__ void ds_rd2(f32x2& d, unsigned a, int o0, int o1) {
    asm volatile("ds_read2_b32 %0, %1 offset0:%2 offset1:%3"
                 : "=v"(d) : "v"(a), "i"(o0), "i"(o1));
}
__device__ __forceinline__ void wait_lgkm0_fence() {
    asm volatile("s_waitcnt lgkmcnt(0)" ::: "memory");
    __builtin_amdgcn_sched_barrier(0);
}
// LDS-only barrier: orders ring handoffs without draining the store queue.
__device__ __forceinline__ void lds_barrier() {
    __builtin_amdgcn_sched_barrier(0);
    asm volatile("s_waitcnt lgkmcnt(0)" ::: "memory");
    __builtin_amdgcn_s_barrier();
    __builtin_amdgcn_sched_barrier(0);
}

// gathers + 32 ticks (flush handled by the caller, before this).
template <bool W0, bool MASKED>
__device__ __forceinline__ void do_chunk(
    const int T0, const int bl, const int lane, const bool lane0,
    const float* __restrict__ g_arr, const float* __restrict__ b_arr,
    const float* __restrict__ lf_ring, float* __restrict__ my_ring,
    const unsigned g_base, const unsigned b_base, const unsigned lf_base,
    float& prev_own, float& prev_left)
{
    if (!MASKED) {
        // ---- paired gathers: 16 read2 (g) + 16 read2 / 8 b128 (hb) ----
        f32x2 g2[16], h2[16];
        const unsigned ga = g_base + 4u * (unsigned)(bl - lane);
        #pragma unroll
        for (int q = 0; q < 16; ++q) ds_rd2(g2[q], ga, 2 * q, 2 * q + 1);
        f32x4 hb4[8];
        if (W0) {
            const unsigned ba = b_base + 4u * (unsigned)T0;
            #pragma unroll
            for (int q = 0; q < 8; ++q) ds_rd128(hb4[q], ba, 16 * q);
        } else {
            // col 63 of slots (bl&127)+4q .. +3  (no wrap: bl&127 <= 96)
            const unsigned hbase = lf_base + ((unsigned)(bl & (RSLOT - 1)) << 8);
            #pragma unroll
            for (int q = 0; q < 8; ++q) {
                const unsigned a = hbase + (unsigned)(q << 10);
                ds_rd2(h2[2*q+0], a, 63, 127);
                ds_rd2(h2[2*q+1], a, 191, 255);
            }
        }
        wait_lgkm0_fence();

        const int m0 = bl - lane;
        #pragma unroll
        for (int s = 0; s < KCH; ++s) {
            const float gg = g2[s >> 1][s & 1];
            const float hb = W0 ? hb4[s >> 2][s & 3] : h2[s >> 1][s & 1];
            float cl = dpp_shr1(prev_own);
            float ct;
            if (W0) { ct = (lane0 ? hb : 0.0f) - prev_left; }
            else    { cl += lane0 ? hb : 0.0f;
                      ct = 0.0f - prev_left; }
            const float x = fmaf(gg, cl, fmaf(gg, prev_own, ct));
            my_ring[(((m0 + s) & (RSLOT - 1)) << 6) + lane] = x;
            prev_left = cl;
            prev_own  = x;
        }
    } else {
        // ---- masked edges (~5 chunks/wave): R9 body ----
        const int m0 = bl - lane;
        #pragma unroll
        for (int s = 0; s < KCH; ++s) {
            const int li = min(max(m0 + s, 0), LLEN - 1);
            const float gg = g_arr[li];
            float hb;
            if (W0) hb = b_arr[T0 + s];                 // pad covers range
            else    hb = lf_ring[(((bl + s) & (RSLOT - 1)) << 6) + 63];
            float cl = dpp_shr1(prev_own);
            float ct;
            if (W0) { ct = (lane0 ? hb : 0.0f) - prev_left; }
            else    { cl += lane0 ? hb : 0.0f;
                      ct = 0.0f - prev_left; }
            const float x = fmaf(gg, cl, fmaf(gg, prev_own, ct));
            my_ring[(((m0 + s) & (RSLOT - 1)) << 6) + lane] = x;
            const bool act = (unsigned)(m0 + s) < (unsigned)LLEN;
            prev_left = act ? cl : prev_left;
            prev_own  = act ? x  : prev_own;
        }
    }
}

__global__ __launch_bounds__(256, 1)
void toeplitz_scan(const float* __restrict__ vin,   // inputs (L, 256)
                   const float* __restrict__ dtin,  // dt     (L, 256)
                   float* __restrict__ out)         // (L, 256, 256)
{
    extern __shared__ float lds[];
    float* g_arr = lds + G_OFF;   // [GPAD]
    float* b_arr = lds + B_OFF;   // [GPAD]
    float* ring  = lds + R_OFF;   // [4][RSLOT][64], row-indexed slots

    const int ch  = blockIdx.x;
    const int tid = threadIdx.x;

    // ---- per-channel g[l], beta[l] (+ pad) ----
    #pragma unroll
    for (int k = 0; k < LLEN / 256; ++k) {
        const int l = tid + 256 * k;
        const float d = dtin[l * NCHAN + ch];
        const float u = vin[l * NCHAN + ch];
        const float ic = 1.0f / (1.0f + 0.25f * d);
        g_arr[l] = (1.0f - 0.25f * d) * ic;
        b_arr[l] = d * u * ic;
    }
    if (tid < GPAD - LLEN) {
        g_arr[LLEN + tid] = 1.0f;
        b_arr[LLEN + tid] = 0.0f;
    }
    __syncthreads();

    const int wave = tid >> 6, lane = tid & 63;
    const bool w0    = (wave == 0);
    const bool lane0 = (lane == 0);
    const int wskew  = wave * SKEW;

    float* my_ring = ring + wave * (RSLOT * 64);
    const float* lf_ring = ring + (wave > 0 ? (wave - 1) : 0) * (RSLOT * 64);
    const unsigned g_base  = lds_a(g_arr);
    const unsigned b_base  = lds_a(b_arr);
    const unsigned my_base = lds_a(my_ring);
    const unsigned lf_base = lds_a(lf_ring);

    float prev_own = 0.0f, prev_left = 0.0f;

    const int rq = lane >> 4;              // flush: row within 4-row group
    const int cq = (lane & 15) << 2;       // flush: col-quad start (dwords)
    float* const out_col = out + (size_t)(ch * 256 + wave * 64 + cq);

    for (int c = 0; c < NCHUNK; ++c) {
        const int T0 = c * KCH;
        const int bl = T0 - wskew;         // lane0's row at s=0 (mult of 32)

        // ---- EARLY FLUSH (lag 96): reads -> wait -> stores, then compute --
        const int F = bl - 96;
        if (F >= 0 && F <= LLEN - KCH) {
            f32x4 v[8];
            const unsigned fb = my_base +
                (unsigned)((((F & (RSLOT - 1)) + rq) << 8) + ((lane & 15) << 4));
            #pragma unroll
            for (int q = 0; q < 8; ++q) ds_rd128(v[q], fb, q * 1024);
            wait_lgkm0_fence();
            float* ob = out_col + (size_t)(F + rq) * (NCHAN * 256);
            #pragma unroll
            for (int q = 0; q < 8; ++q) {
                __builtin_nontemporal_store(v[q], reinterpret_cast<f32x4*>(ob));
                ob += (size_t)4 * (NCHAN * 256);
            }
            __builtin_amdgcn_sched_barrier(0);   // stores stay here
        }

        if (bl >= 0 && bl <= 1056) {       // any lane has active ticks
            const bool fast = (bl >= 64) && (bl <= LLEN - KCH);
            if (w0) {
                if (fast)
                    do_chunk<true, false>(T0, bl, lane, lane0, g_arr, b_arr,
                                          lf_ring, my_ring, g_base, b_base,
                                          lf_base, prev_own, prev_left);
                else
                    do_chunk<true, true>(T0, bl, lane, lane0, g_arr, b_arr,
                                         lf_ring, my_ring, g_base, b_base,
                                         lf_base, prev_own, prev_left);
            } else {
                if (fast)
                    do_chunk<false, false>(T0, bl, lane, lane0, g_arr, b_arr,
                                           lf_ring, my_ring, g_base, b_base,
                                           lf_base, prev_own, prev_left);
                else
                    do_chunk<false, true>(T0, bl, lane, lane0, g_arr, b_arr,
                                          lf_ring, my_ring, g_base, b_base,
                                          lf_base, prev_own, prev_left);
            }
        }
        lds_barrier();
    }
}

} // namespace

extern "C" void kernel_launch(void* const* d_in, const int* in_sizes, int n_in,
                              void* d_out, int out_size, void* d_ws, size_t ws_size,
                              hipStream_t stream) {
    (void)in_sizes; (void)n_in; (void)d_ws; (void)ws_size; (void)out_size;
    const float* vin  = (const float*)d_in[0];   // "inputs"
    const float* dtin = (const float*)d_in[1];   // "dt"
    float* out = (float*)d_out;

    (void)hipFuncSetAttribute(reinterpret_cast<const void*>(toeplitz_scan),
                              hipFuncAttributeMaxDynamicSharedMemorySize,
                              (int)LDS_BYTES);

    toeplitz_scan<<<NCHAN, 256, LDS_BYTES, stream>>>(vin, dtin, out);
}

// Round 15
// 67.832 us; speedup vs baseline: 1.2092x; 1.0037x over previous
//
#include <hip/hip_runtime.h>

// ToeplitzMemoryProjection (HiPPO LagT, alpha=0.5 bilinear).
//
// Recurrence (exact in the truncated lower-tri Toeplitz algebra, verified
// rounds 1-14): with c = 1+0.25dt, g = (1-0.25dt)/c, beta = dt*u/c,
//   x_l[i] = g_l*(x_l[i-1] + x_{l-1}[i]) - x_{l-1}[i-1] + beta_l*[i==0]
//
// R15 = R9 (best, 65.6us) + ONE change: the cross-wave handoff gather for
// waves 1-3 (32 broadcast b32 reads of left ring's col 63, ~186cy of DS
// pipe per wave) is replaced by ONE ds_read_b32 (lane t in [0,32) reads
// slot (bl+t), col 63 -- 32 distinct addrs all in bank 31, a deliberate
// 32-way conflict ~64cy) + 32 independent v_readlane redistributions on
// the otherwise-idle VALU pipe (no serial chain; R13's regression was the
// g DPP chain, not readlane). Everything else byte-identical to R9:
//  - column-per-lane wavefront, KCH=32, SKEW=96, row-indexed ring
//    RSLOT=128 (slot = row & 127), write bank = lane%32 (free).
//  - flush rows [T0-wskew-64, +31] at chunk end: 8 ds_read_b128 + 8
//    nontemporal dwordx4, coalesced 256B/row-quad segments.
//  - LDS-only barriers (no vmcnt drain): store queue drains in background
//    (confirmed: R10/R11/R12/R14 store-motion experiments all neutral).
//  - W0's hb = beta via 8 aligned b128 (already cheap, kept).

namespace {

constexpr int LLEN   = 1024;
constexpr int NCHAN  = 256;
constexpr int KCH    = 32;                 // ticks per chunk
constexpr int SKEW   = 96;                 // wave skew; 96-63=33 > KCH-1
constexpr int RSLOT  = 128;                // row slots per ring (pow2)
constexpr int NCHUNK = 43;                 // covers ticks [0,1376) >= 1375
constexpr int GPAD   = 1152;               // g/b padded length

constexpr int G_OFF = 0;
constexpr int B_OFF = GPAD;
constexpr int R_OFF = 2 * GPAD;
constexpr int LDS_FLOATS = R_OFF + 4 * RSLOT * 64;
constexpr size_t LDS_BYTES = (size_t)LDS_FLOATS * 4;   // 140288 B

using f32x4 = __attribute__((ext_vector_type(4))) float;

__device__ __forceinline__ float dpp_shr1(float v) {
    // lane i <- lane i-1; lane 0 <- 0
    return __int_as_float(__builtin_amdgcn_update_dpp(
        0, __float_as_int(v), 0x138 /*WAVE_SHR1*/, 0xF, 0xF, false));
}
__device__ __forceinline__ float rdlane(float v, int s) {
    return __int_as_float(__builtin_amdgcn_readlane(__float_as_int(v), s));
}
__device__ __forceinline__ void compiler_mem_fence() {
    asm volatile("" ::: "memory");
}
// LDS-only barrier: orders ring handoffs without draining the store queue.
__device__ __forceinline__ void lds_barrier() {
    __builtin_amdgcn_sched_barrier(0);
    asm volatile("s_waitcnt lgkmcnt(0)" ::: "memory");
    __builtin_amdgcn_s_barrier();
    __builtin_amdgcn_sched_barrier(0);
}

// One 32-tick chunk. hb source: W0 -> b_arr (beta, aligned b128);
// else -> left wave's ring col 63: 1 conflict-read + readlane fan-out.
template <bool W0, bool MASKED>
__device__ __forceinline__ void do_chunk(
    const int T0, const int bl, const int lane, const bool lane0,
    const float* __restrict__ g_arr, const float* __restrict__ hb_src,
    float* __restrict__ my_ring, float& prev_own, float& prev_left)
{
    float hb[KCH];
    if (W0) {
        #pragma unroll
        for (int q = 0; q < KCH / 4; ++q) {
            const f32x4 t =
                *reinterpret_cast<const f32x4*>(hb_src + T0 + 4 * q);
            hb[4*q+0] = t[0]; hb[4*q+1] = t[1];
            hb[4*q+2] = t[2]; hb[4*q+3] = t[3];
        }
    } else if (!MASKED) {
        // one read: lane t (t = lane&31) fetches slot (bl+t), col 63.
        // (bl&127) <= 96, t <= 31 -> no wrap inside the mask window.
        const int t = lane & 31;
        const float hvv = hb_src[(((bl + t) & (RSLOT - 1)) << 6) + 63];
        #pragma unroll
        for (int s = 0; s < KCH; ++s) hb[s] = rdlane(hvv, s);  // uniform
    } else {
        #pragma unroll
        for (int s = 0; s < KCH; ++s)
            hb[s] = hb_src[(((bl + s) & (RSLOT - 1)) << 6) + 63];
    }

    const int m0 = bl - lane;              // this lane's row at s=0
    #pragma unroll
    for (int s = 0; s < KCH; ++s) {
        int li = m0 + s;
        if (MASKED) li = min(max(li, 0), LLEN - 1);
        const float gg = g_arr[li];
        float cl = dpp_shr1(prev_own);
        float ct;
        if (W0) {
            ct = (lane0 ? hb[s] : 0.0f) - prev_left;   // lane0: +beta
        } else {
            cl += lane0 ? hb[s] : 0.0f;                // lane0: handoff
            ct = 0.0f - prev_left;
        }
        const float x = fmaf(gg, cl, fmaf(gg, prev_own, ct));
        my_ring[(((m0 + s) & (RSLOT - 1)) << 6) + lane] = x;
        if (MASKED) {
            const bool act = (unsigned)(m0 + s) < (unsigned)LLEN;
            prev_left = act ? cl : prev_left;
            prev_own  = act ? x  : prev_own;
        } else {
            prev_left = cl;
            prev_own  = x;
        }
    }
}

__global__ __launch_bounds__(256, 1)
void toeplitz_scan(const float* __restrict__ vin,   // inputs (L, 256)
                   const float* __restrict__ dtin,  // dt     (L, 256)
                   float* __restrict__ out)         // (L, 256, 256)
{
    extern __shared__ float lds[];
    float* g_arr = lds + G_OFF;   // [GPAD]
    float* b_arr = lds + B_OFF;   // [GPAD]
    float* ring  = lds + R_OFF;   // [4][RSLOT][64], row-indexed slots

    const int ch  = blockIdx.x;
    const int tid = threadIdx.x;

    // ---- per-channel g[l], beta[l] (+ zero pad) ----
    #pragma unroll
    for (int k = 0; k < LLEN / 256; ++k) {
        const int l = tid + 256 * k;
        const float d = dtin[l * NCHAN + ch];
        const float u = vin[l * NCHAN + ch];
        const float ic = 1.0f / (1.0f + 0.25f * d);
        g_arr[l] = (1.0f - 0.25f * d) * ic;
        b_arr[l] = d * u * ic;
    }
    if (tid < GPAD - LLEN) {
        g_arr[LLEN + tid] = 1.0f;
        b_arr[LLEN + tid] = 0.0f;
    }
    __syncthreads();

    const int wave = tid >> 6, lane = tid & 63;
    const bool w0    = (wave == 0);
    const bool lane0 = (lane == 0);
    const int wskew  = wave * SKEW;

    float* my_ring = ring + wave * (RSLOT * 64);
    const float* lf_ring = ring + (wave > 0 ? (wave - 1) : 0) * (RSLOT * 64);

    float prev_own = 0.0f, prev_left = 0.0f;

    const int rq = lane >> 4;              // flush: row within 4-row group
    const int cq = (lane & 15) << 2;       // flush: col-quad start
    float* const out_col = out + (size_t)(ch * 256 + wave * 64 + cq);

    for (int c = 0; c < NCHUNK; ++c) {
        const int T0 = c * KCH;
        const int bl = T0 - wskew;         // lane0's row at s=0 (mult of 32)

        if (bl >= 0 && bl <= 1056) {       // any lane active this chunk
            const bool fast = (bl >= 64) && (bl <= LLEN - KCH);
            if (w0) {
                if (fast)
                    do_chunk<true, false>(T0, bl, lane, lane0, g_arr, b_arr,
                                          my_ring, prev_own, prev_left);
                else
                    do_chunk<true, true>(T0, bl, lane, lane0, g_arr, b_arr,
                                         my_ring, prev_own, prev_left);
            } else {
                if (fast)
                    do_chunk<false, false>(T0, bl, lane, lane0, g_arr, lf_ring,
                                           my_ring, prev_own, prev_left);
                else
                    do_chunk<false, true>(T0, bl, lane, lane0, g_arr, lf_ring,
                                          my_ring, prev_own, prev_left);
            }
        }

        // ---- flush rows [F, F+31] (4-row groups; complete at tick T0+30) --
        const int F = T0 - wskew - 64;
        if (F >= 0 && F <= LLEN - KCH) {
            compiler_mem_fence();          // ring writes stay above reads
            const float* rb = my_ring + ((F & (RSLOT - 1)) << 6) + cq;
            float* ob = out_col + (size_t)(F + rq) * (NCHAN * 256);
            #pragma unroll
            for (int q = 0; q < 8; ++q) {
                const f32x4 v =
                    *reinterpret_cast<const f32x4*>(rb + ((4 * q + rq) << 6));
                __builtin_nontemporal_store(v, reinterpret_cast<f32x4*>(ob));
                ob += (size_t)4 * (NCHAN * 256);
            }
        }
        lds_barrier();
    }
}

} // namespace

extern "C" void kernel_launch(void* const* d_in, const int* in_sizes, int n_in,
                              void* d_out, int out_size, void* d_ws, size_t ws_size,
                              hipStream_t stream) {
    (void)in_sizes; (void)n_in; (void)d_ws; (void)ws_size; (void)out_size;
    const float* vin  = (const float*)d_in[0];   // "inputs"
    const float* dtin = (const float*)d_in[1];   // "dt"
    float* out = (float*)d_out;

    (void)hipFuncSetAttribute(reinterpret_cast<const void*>(toeplitz_scan),
                              hipFuncAttributeMaxDynamicSharedMemorySize,
                              (int)LDS_BYTES);

    toeplitz_scan<<<NCHAN, 256, LDS_BYTES, stream>>>(vin, dtin, out);
}